// Round 2
// baseline (336.894 us; speedup 1.0000x reference)
//
#include <hip/hip_runtime.h>

// Swin cross-attention, split-pipeline version for MI355X.
// C=256, HEADS=2, dh=128, WS=8, T=64 tokens/window, 680 windows total.
// Per phase: proj (QKV GEMMs, LDS-staged windows) -> attn (QK^T/softmax/PV,
// direct-global fragments) -> oproj (Wo GEMM + residual + relu, no LDS).
// Falls back to the round-1 fused kernel if ws_size is too small.

using bf16x8 = __attribute__((ext_vector_type(8))) __bf16;
using f32x4  = __attribute__((ext_vector_type(4))) float;
using u16x4  = __attribute__((ext_vector_type(4))) unsigned short;
using u16x8  = __attribute__((ext_vector_type(8))) unsigned short;

__device__ __forceinline__ unsigned short f2bf(float f){
  unsigned int x = __float_as_uint(f);
  x += 0x7FFFu + ((x >> 16) & 1u);          // RNE
  return (unsigned short)(x >> 16);
}

__device__ __forceinline__ void store_bf4(unsigned short* dst, f32x4 v){
  u16x4 o;
  o[0]=f2bf(v[0]); o[1]=f2bf(v[1]); o[2]=f2bf(v[2]); o[3]=f2bf(v[3]);
  *reinterpret_cast<u16x4*>(dst) = o;       // 8B packed store
}

#define MFMA16 __builtin_amdgcn_mfma_f32_16x16x32_bf16

__global__ void wcvt_kernel(const float* __restrict__ w1,
                            const float* __restrict__ w2,
                            unsigned short* __restrict__ dst){
  int i = blockIdx.x * 256 + threadIdx.x;   // 524288 float4s total
  const float4* src = (i < 262144) ? (reinterpret_cast<const float4*>(w1) + i)
                                   : (reinterpret_cast<const float4*>(w2) + (i - 262144));
  float4 v = *src;
  u16x4 o; o[0]=f2bf(v.x); o[1]=f2bf(v.y); o[2]=f2bf(v.z); o[3]=f2bf(v.w);
  reinterpret_cast<u16x4*>(dst)[i] = o;
}

// ---- shared window-geometry decode ------------------------------------------
struct WinGeo {
  int H, W, b;
  size_t HW, CHW, ooff, winoff;
  const float* feat;
};

__device__ __forceinline__ WinGeo decode_win(int win,
    const float* g0, const float* g1, const float* g2, const float* g3){
  WinGeo g;
  int lvl, wloc;
  if (win < 512){ lvl = 0; wloc = win; }
  else if (win < 640){ lvl = 1; wloc = win - 512; }
  else if (win < 672){ lvl = 2; wloc = win - 640; }
  else { lvl = 3; wloc = win - 672; }
  if (lvl == 0){ g.H = 128; g.ooff = 0;        g.feat = g0; }
  else if (lvl == 1){ g.H = 64; g.ooff = 16777216; g.feat = g1; }
  else if (lvl == 2){ g.H = 32; g.ooff = 20971520; g.feat = g2; }
  else { g.H = 16; g.ooff = 22020096; g.feat = g3; }
  g.W = g.H;
  int nww = g.H >> 3, npb = nww * nww;
  g.b = wloc / npb;
  int r = wloc - g.b * npb;
  int whh = r / nww, www = r - whh * nww;
  g.HW = (size_t)g.H * g.W; g.CHW = g.HW * 256;
  g.winoff = (size_t)(whh * 8) * g.W + (size_t)(www * 8);
  return g;
}

// stage one fp32 window (channel-major) -> LDS bf16 [64][264]
__device__ __forceinline__ void stage_window(const float* __restrict__ src,
    unsigned short* __restrict__ lds, int W, size_t HW, int w, int l){
  int hi0 = l >> 3, wi0 = l & 7;
  const float* p0 = src + (size_t)hi0 * W + wi0;
  #pragma unroll
  for (int oc = 0; oc < 8; ++oc){
    int c0 = (oc * 4 + w) * 8;
    const float* p = p0 + (size_t)c0 * HW;
    u16x8 uv;
    #pragma unroll
    for (int j = 0; j < 8; ++j) uv[j] = f2bf(p[(size_t)j * HW]);
    *reinterpret_cast<u16x8*>(&lds[l * 264 + c0]) = uv;
  }
}

// A = weight rows (global bf16 [256][256]), B = LDS token rows -> dst[t*256+d] bf16
__device__ __forceinline__ void gemm_w_lds_store_td(
    const unsigned short* __restrict__ Wm, const unsigned short* __restrict__ lds,
    unsigned short* __restrict__ dst, int wd, int l15, int l4){
  f32x4 acc[4][4];
  #pragma unroll
  for (int i = 0; i < 4; ++i)
    #pragma unroll
    for (int j = 0; j < 4; ++j) acc[i][j] = f32x4{0.f,0.f,0.f,0.f};
  #pragma unroll
  for (int ks = 0; ks < 8; ++ks){
    int k0 = ks * 32 + l4 * 8;
    bf16x8 a[4], bb[4];
    #pragma unroll
    for (int mi = 0; mi < 4; ++mi)
      a[mi] = *reinterpret_cast<const bf16x8*>(Wm + (size_t)((wd + mi*16 + l15) * 256 + k0));
    #pragma unroll
    for (int ni = 0; ni < 4; ++ni)
      bb[ni] = *reinterpret_cast<const bf16x8*>(&lds[(ni*16 + l15) * 264 + k0]);
    #pragma unroll
    for (int mi = 0; mi < 4; ++mi)
      #pragma unroll
      for (int ni = 0; ni < 4; ++ni)
        acc[mi][ni] = MFMA16(a[mi], bb[ni], acc[mi][ni], 0, 0, 0);
  }
  #pragma unroll
  for (int mi = 0; mi < 4; ++mi){
    int d0 = wd + mi*16 + l4*4;
    #pragma unroll
    for (int ni = 0; ni < 4; ++ni)
      store_bf4(dst + (size_t)(ni*16 + l15) * 256 + d0, acc[mi][ni]);
  }
}

// A = LDS token rows (u), B = weight rows (d) -> dst = V^T[d*64+u] bf16
__device__ __forceinline__ void gemm_lds_w_store_vt(
    const unsigned short* __restrict__ lds, const unsigned short* __restrict__ Wm,
    unsigned short* __restrict__ dst, int wd, int l15, int l4){
  f32x4 acc[4][4];
  #pragma unroll
  for (int i = 0; i < 4; ++i)
    #pragma unroll
    for (int j = 0; j < 4; ++j) acc[i][j] = f32x4{0.f,0.f,0.f,0.f};
  #pragma unroll
  for (int ks = 0; ks < 8; ++ks){
    int k0 = ks * 32 + l4 * 8;
    bf16x8 a[4], bb[4];
    #pragma unroll
    for (int mi = 0; mi < 4; ++mi)
      a[mi] = *reinterpret_cast<const bf16x8*>(&lds[(mi*16 + l15) * 264 + k0]);
    #pragma unroll
    for (int ni = 0; ni < 4; ++ni)
      bb[ni] = *reinterpret_cast<const bf16x8*>(Wm + (size_t)((wd + ni*16 + l15) * 256 + k0));
    #pragma unroll
    for (int mi = 0; mi < 4; ++mi)
      #pragma unroll
      for (int ni = 0; ni < 4; ++ni)
        acc[mi][ni] = MFMA16(a[mi], bb[ni], acc[mi][ni], 0, 0, 0);
  }
  #pragma unroll
  for (int mi = 0; mi < 4; ++mi){
    int u0 = mi*16 + l4*4;
    #pragma unroll
    for (int ni = 0; ni < 4; ++ni)
      store_bf4(dst + (size_t)(wd + ni*16 + l15) * 64 + u0, acc[mi][ni]);
  }
}

// ---- P1: projections. blocks 0..679 = Q (from X); 680..1359 = K+V (from Y) ---
__global__ __launch_bounds__(256, 3) void proj_kernel(
    const float* __restrict__ g0, const float* __restrict__ g1,
    const float* __restrict__ g2, const float* __restrict__ g3,
    const float* __restrict__ outb_r, const unsigned short* __restrict__ wball,
    unsigned short* __restrict__ Qb, unsigned short* __restrict__ Kb,
    unsigned short* __restrict__ VTb, int phase)
{
  __shared__ alignas(16) unsigned short R0[64*264];
  int bid = blockIdx.x;
  bool isQ = bid < 680;
  int win = isQ ? bid : bid - 680;
  WinGeo g = decode_win(win, g0, g1, g2, g3);

  const float* src;
  if (isQ){
    src = (phase == 0) ? g.feat + (size_t)g.b * g.CHW + g.winoff
                       : g.feat + (size_t)(g.b + 2) * g.CHW + g.winoff;
  } else {
    src = (phase == 0) ? g.feat + (size_t)(g.b + 2) * g.CHW + g.winoff
                       : outb_r + g.ooff + (size_t)g.b * g.CHW + g.winoff;
  }
  const unsigned short* Wbase = wball + ((size_t)(phase * 16 + (win >= 672 ? 3 : win >= 640 ? 2 : win >= 512 ? 1 : 0) * 4) << 16);

  int tid = threadIdx.x;
  int w = tid >> 6, l = tid & 63, l15 = l & 15, l4 = l >> 4, wd = w * 64;

  stage_window(src, R0, g.W, g.HW, w, l);
  __syncthreads();

  size_t woff = (size_t)win << 14;   // win*16384
  if (isQ){
    gemm_w_lds_store_td(Wbase /*Wq*/, R0, Qb + woff, wd, l15, l4);
  } else {
    gemm_w_lds_store_td(Wbase + 65536 /*Wk*/, R0, Kb + woff, wd, l15, l4);
    gemm_lds_w_store_vt(R0, Wbase + 2*65536 /*Wv*/, VTb + woff, wd, l15, l4);
  }
}

// ---- P2: attention per window. Q/K/V^T fragments direct from global. --------
__global__ __launch_bounds__(256, 4) void attn_kernel(
    const unsigned short* __restrict__ Qb, const unsigned short* __restrict__ Kb,
    const unsigned short* __restrict__ VTb, unsigned short* __restrict__ Ob)
{
  __shared__ alignas(16) unsigned short Plds[2*64*72];   // 18432 B
  int win = blockIdx.x;
  size_t woff = (size_t)win << 14;
  const unsigned short* Qw = Qb + woff;
  const unsigned short* Kw = Kb + woff;
  const unsigned short* VTw = VTb + woff;
  unsigned short* Ow = Ob + woff;

  int tid = threadIdx.x;
  int w = tid >> 6, l = tid & 63, l15 = l & 15, l4 = l >> 4;
  int h = w >> 1, tc = w & 1;

  // S^T[u][t] for head h, t-range tc*32..+32
  f32x4 s[4][2];
  #pragma unroll
  for (int i = 0; i < 4; ++i){ s[i][0] = f32x4{0.f,0.f,0.f,0.f}; s[i][1] = f32x4{0.f,0.f,0.f,0.f}; }
  #pragma unroll
  for (int ks = 0; ks < 4; ++ks){
    int k0 = h * 128 + ks * 32 + l4 * 8;
    bf16x8 a[4], bb[2];
    #pragma unroll
    for (int mi = 0; mi < 4; ++mi)
      a[mi] = *reinterpret_cast<const bf16x8*>(Kw + (size_t)(mi*16 + l15) * 256 + k0);
    #pragma unroll
    for (int ni = 0; ni < 2; ++ni)
      bb[ni] = *reinterpret_cast<const bf16x8*>(Qw + (size_t)(tc*32 + ni*16 + l15) * 256 + k0);
    #pragma unroll
    for (int mi = 0; mi < 4; ++mi)
      #pragma unroll
      for (int ni = 0; ni < 2; ++ni)
        s[mi][ni] = MFMA16(a[mi], bb[ni], s[mi][ni], 0, 0, 0);
  }

  const float SCL = 0.08838834764831845f;   // 1/sqrt(128)
  #pragma unroll
  for (int ni = 0; ni < 2; ++ni){
    float m = s[0][ni][0];
    #pragma unroll
    for (int mi = 0; mi < 4; ++mi)
      #pragma unroll
      for (int reg = 0; reg < 4; ++reg) m = fmaxf(m, s[mi][ni][reg]);
    m = fmaxf(m, __shfl_xor(m, 16));
    m = fmaxf(m, __shfl_xor(m, 32));
    float sum = 0.f;
    #pragma unroll
    for (int mi = 0; mi < 4; ++mi)
      #pragma unroll
      for (int reg = 0; reg < 4; ++reg){
        float e = __expf((s[mi][ni][reg] - m) * SCL);
        s[mi][ni][reg] = e; sum += e;
      }
    sum += __shfl_xor(sum, 16);
    sum += __shfl_xor(sum, 32);
    float rs = 1.0f / sum;
    int t = tc*32 + ni*16 + l15;
    #pragma unroll
    for (int mi = 0; mi < 4; ++mi){
      f32x4 pv;
      #pragma unroll
      for (int reg = 0; reg < 4; ++reg) pv[reg] = s[mi][ni][reg] * rs;
      store_bf4(&Plds[h * 4608 + t * 72 + mi*16 + l4*4], pv);
    }
  }
  __syncthreads();   // all Q/K reads consumed; P visible

  // O^T[c][t] = V^T * P^T  -> store O[t][c] bf16 (aliased onto Q region is OK)
  {
    int wdh = w * 64;
    f32x4 acc[4][4];
    #pragma unroll
    for (int i = 0; i < 4; ++i)
      #pragma unroll
      for (int j = 0; j < 4; ++j) acc[i][j] = f32x4{0.f,0.f,0.f,0.f};
    #pragma unroll
    for (int ks = 0; ks < 2; ++ks){
      int k0 = ks * 32 + l4 * 8;
      bf16x8 a[4], bb[4];
      #pragma unroll
      for (int mi = 0; mi < 4; ++mi)
        a[mi] = *reinterpret_cast<const bf16x8*>(VTw + (size_t)(wdh + mi*16 + l15) * 64 + k0);
      #pragma unroll
      for (int ni = 0; ni < 4; ++ni)
        bb[ni] = *reinterpret_cast<const bf16x8*>(&Plds[h * 4608 + (ni*16 + l15) * 72 + k0]);
      #pragma unroll
      for (int mi = 0; mi < 4; ++mi)
        #pragma unroll
        for (int ni = 0; ni < 4; ++ni)
          acc[mi][ni] = MFMA16(a[mi], bb[ni], acc[mi][ni], 0, 0, 0);
    }
    #pragma unroll
    for (int mi = 0; mi < 4; ++mi){
      int c0 = wdh + mi*16 + l4*4;
      #pragma unroll
      for (int ni = 0; ni < 4; ++ni)
        store_bf4(Ow + (size_t)(ni*16 + l15) * 256 + c0, acc[mi][ni]);
    }
  }
}

// ---- P3: out = relu(x + O*Wo^T), fragments direct from global, no LDS -------
__global__ __launch_bounds__(256, 4) void oproj_kernel(
    const float* __restrict__ g0, const float* __restrict__ g1,
    const float* __restrict__ g2, const float* __restrict__ g3,
    const unsigned short* __restrict__ wball, const unsigned short* __restrict__ Ob,
    float* __restrict__ outb, int phase)
{
  int win = blockIdx.x;
  WinGeo g = decode_win(win, g0, g1, g2, g3);
  const float* xsrc = (phase == 0) ? g.feat + (size_t)g.b * g.CHW + g.winoff
                                   : g.feat + (size_t)(g.b + 2) * g.CHW + g.winoff;
  float* outp = outb + g.ooff + (size_t)((phase == 0) ? g.b : g.b + 2) * g.CHW + g.winoff;
  int lvl = (win >= 672) ? 3 : (win >= 640) ? 2 : (win >= 512) ? 1 : 0;
  const unsigned short* Wo = wball + ((size_t)(phase * 16 + lvl * 4 + 3) << 16);
  const unsigned short* Ow = Ob + ((size_t)win << 14);

  int tid = threadIdx.x;
  int w = tid >> 6, l = tid & 63, l15 = l & 15, l4 = l >> 4, wd = w * 64;

  f32x4 acc[4][4];
  #pragma unroll
  for (int i = 0; i < 4; ++i)
    #pragma unroll
    for (int j = 0; j < 4; ++j) acc[i][j] = f32x4{0.f,0.f,0.f,0.f};
  #pragma unroll
  for (int ks = 0; ks < 8; ++ks){
    int k0 = ks * 32 + l4 * 8;
    bf16x8 a[4], bb[4];
    #pragma unroll
    for (int mi = 0; mi < 4; ++mi)
      a[mi] = *reinterpret_cast<const bf16x8*>(Wo + (size_t)((wd + mi*16 + l15) * 256 + k0));
    #pragma unroll
    for (int ni = 0; ni < 4; ++ni)
      bb[ni] = *reinterpret_cast<const bf16x8*>(Ow + (size_t)(ni*16 + l15) * 256 + k0);
    #pragma unroll
    for (int mi = 0; mi < 4; ++mi)
      #pragma unroll
      for (int ni = 0; ni < 4; ++ni)
        acc[mi][ni] = MFMA16(a[mi], bb[ni], acc[mi][ni], 0, 0, 0);
  }
  #pragma unroll
  for (int mi = 0; mi < 4; ++mi){
    #pragma unroll
    for (int ni = 0; ni < 4; ++ni){
      int t = ni*16 + l15, thi = t >> 3, twi = t & 7;
      size_t base = (size_t)(wd + mi*16 + l4*4) * g.HW + (size_t)thi * g.W + twi;
      #pragma unroll
      for (int reg = 0; reg < 4; ++reg){
        float res = xsrc[base + (size_t)reg * g.HW];
        float v = acc[mi][ni][reg] + res;
        outp[base + (size_t)reg * g.HW] = fmaxf(v, 0.f);
      }
    }
  }
}

// ======================= round-1 fused fallback ==============================
__global__ __launch_bounds__(256, 1) void swin_phase(
    const float* __restrict__ g0, const float* __restrict__ g1,
    const float* __restrict__ g2, const float* __restrict__ g3,
    const unsigned short* __restrict__ wball,
    float* __restrict__ outb, int phase)
{
  __shared__ alignas(16) unsigned short R0[64*264];
  __shared__ alignas(16) unsigned short R1[64*264];
  __shared__ alignas(16) unsigned short R2[256*72];
  __shared__ alignas(16) unsigned short R3[64*264];

  int bid = blockIdx.x;
  WinGeo g = decode_win(bid, g0, g1, g2, g3);
  int lvl = (bid >= 672) ? 3 : (bid >= 640) ? 2 : (bid >= 512) ? 1 : 0;

  const float* xsrc; const float* ysrc; float* outp;
  if (phase == 0){
    xsrc = g.feat + (size_t)g.b * g.CHW + g.winoff;
    ysrc = g.feat + (size_t)(g.b + 2) * g.CHW + g.winoff;
    outp = outb + g.ooff + (size_t)g.b * g.CHW + g.winoff;
  } else {
    xsrc = g.feat + (size_t)(g.b + 2) * g.CHW + g.winoff;
    ysrc = outb + g.ooff + (size_t)g.b * g.CHW + g.winoff;
    outp = outb + g.ooff + (size_t)(g.b + 2) * g.CHW + g.winoff;
  }
  const unsigned short* Wq = wball + ((size_t)(phase * 16 + lvl * 4) << 16);
  const unsigned short* Wk = Wq + 65536;
  const unsigned short* Wv = Wq + 2 * 65536;
  const unsigned short* Wo = Wq + 3 * 65536;

  int tid = threadIdx.x;
  int w = tid >> 6, l = tid & 63, l15 = l & 15, l4 = l >> 4, wd = w * 64;

  stage_window(ysrc, R0, g.W, g.HW, w, l);
  __syncthreads();

  gemm_w_lds_store_td(Wk, R0, (unsigned short*)0, 0, 0, 0); // placeholder never used
  // (fallback keeps original inline code below)
  {
    f32x4 acc[4][4];
    #pragma unroll
    for (int i = 0; i < 4; ++i)
      #pragma unroll
      for (int j = 0; j < 4; ++j) acc[i][j] = f32x4{0.f,0.f,0.f,0.f};
    #pragma unroll
    for (int ks = 0; ks < 8; ++ks){
      int k0 = ks * 32 + l4 * 8;
      bf16x8 a[4], bb[4];
      #pragma unroll
      for (int mi = 0; mi < 4; ++mi)
        a[mi] = *reinterpret_cast<const bf16x8*>(Wk + (size_t)((wd + mi*16 + l15) * 256 + k0));
      #pragma unroll
      for (int ni = 0; ni < 4; ++ni)
        bb[ni] = *reinterpret_cast<const bf16x8*>(&R0[(ni*16 + l15) * 264 + k0]);
      #pragma unroll
      for (int mi = 0; mi < 4; ++mi)
        #pragma unroll
        for (int ni = 0; ni < 4; ++ni)
          acc[mi][ni] = MFMA16(a[mi], bb[ni], acc[mi][ni], 0, 0, 0);
    }
    #pragma unroll
    for (int mi = 0; mi < 4; ++mi){
      int d0 = wd + mi*16 + l4*4;
      #pragma unroll
      for (int ni = 0; ni < 4; ++ni)
        store_bf4(&R1[(ni*16 + l15) * 264 + d0], acc[mi][ni]);
    }
  }
  {
    f32x4 acc[4][4];
    #pragma unroll
    for (int i = 0; i < 4; ++i)
      #pragma unroll
      for (int j = 0; j < 4; ++j) acc[i][j] = f32x4{0.f,0.f,0.f,0.f};
    #pragma unroll
    for (int ks = 0; ks < 8; ++ks){
      int k0 = ks * 32 + l4 * 8;
      bf16x8 a[4], bb[4];
      #pragma unroll
      for (int mi = 0; mi < 4; ++mi)
        a[mi] = *reinterpret_cast<const bf16x8*>(&R0[(mi*16 + l15) * 264 + k0]);
      #pragma unroll
      for (int ni = 0; ni < 4; ++ni)
        bb[ni] = *reinterpret_cast<const bf16x8*>(Wv + (size_t)((wd + ni*16 + l15) * 256 + k0));
      #pragma unroll
      for (int mi = 0; mi < 4; ++mi)
        #pragma unroll
        for (int ni = 0; ni < 4; ++ni)
          acc[mi][ni] = MFMA16(a[mi], bb[ni], acc[mi][ni], 0, 0, 0);
    }
    #pragma unroll
    for (int mi = 0; mi < 4; ++mi){
      int u0 = mi*16 + l4*4;
      #pragma unroll
      for (int ni = 0; ni < 4; ++ni)
        store_bf4(&R2[(wd + ni*16 + l15) * 72 + u0], acc[mi][ni]);
    }
  }
  __syncthreads();
  stage_window(xsrc, R0, g.W, g.HW, w, l);
  __syncthreads();
  {
    f32x4 acc[4][4];
    #pragma unroll
    for (int i = 0; i < 4; ++i)
      #pragma unroll
      for (int j = 0; j < 4; ++j) acc[i][j] = f32x4{0.f,0.f,0.f,0.f};
    #pragma unroll
    for (int ks = 0; ks < 8; ++ks){
      int k0 = ks * 32 + l4 * 8;
      bf16x8 a[4], bb[4];
      #pragma unroll
      for (int mi = 0; mi < 4; ++mi)
        a[mi] = *reinterpret_cast<const bf16x8*>(Wq + (size_t)((wd + mi*16 + l15) * 256 + k0));
      #pragma unroll
      for (int ni = 0; ni < 4; ++ni)
        bb[ni] = *reinterpret_cast<const bf16x8*>(&R0[(ni*16 + l15) * 264 + k0]);
      #pragma unroll
      for (int mi = 0; mi < 4; ++mi)
        #pragma unroll
        for (int ni = 0; ni < 4; ++ni)
          acc[mi][ni] = MFMA16(a[mi], bb[ni], acc[mi][ni], 0, 0, 0);
    }
    #pragma unroll
    for (int mi = 0; mi < 4; ++mi){
      int d0 = wd + mi*16 + l4*4;
      #pragma unroll
      for (int ni = 0; ni < 4; ++ni)
        store_bf4(&R3[(ni*16 + l15) * 264 + d0], acc[mi][ni]);
    }
  }
  __syncthreads();

  int h = w >> 1, tc = w & 1;
  {
    f32x4 s[4][2];
    #pragma unroll
    for (int i = 0; i < 4; ++i){ s[i][0] = f32x4{0.f,0.f,0.f,0.f}; s[i][1] = f32x4{0.f,0.f,0.f,0.f}; }
    #pragma unroll
    for (int ks = 0; ks < 4; ++ks){
      int k0 = h * 128 + ks * 32 + l4 * 8;
      bf16x8 a[4], bb[2];
      #pragma unroll
      for (int mi = 0; mi < 4; ++mi)
        a[mi] = *reinterpret_cast<const bf16x8*>(&R1[(mi*16 + l15) * 264 + k0]);
      #pragma unroll
      for (int ni = 0; ni < 2; ++ni)
        bb[ni] = *reinterpret_cast<const bf16x8*>(&R3[(tc*32 + ni*16 + l15) * 264 + k0]);
      #pragma unroll
      for (int mi = 0; mi < 4; ++mi)
        #pragma unroll
        for (int ni = 0; ni < 2; ++ni)
          s[mi][ni] = MFMA16(a[mi], bb[ni], s[mi][ni], 0, 0, 0);
    }
    __syncthreads();
    const float SCL = 0.08838834764831845f;
    unsigned short* P = R1;
    #pragma unroll
    for (int ni = 0; ni < 2; ++ni){
      float m = s[0][ni][0];
      #pragma unroll
      for (int mi = 0; mi < 4; ++mi)
        #pragma unroll
        for (int reg = 0; reg < 4; ++reg) m = fmaxf(m, s[mi][ni][reg]);
      m = fmaxf(m, __shfl_xor(m, 16));
      m = fmaxf(m, __shfl_xor(m, 32));
      float sum = 0.f;
      #pragma unroll
      for (int mi = 0; mi < 4; ++mi)
        #pragma unroll
        for (int reg = 0; reg < 4; ++reg){
          float e = __expf((s[mi][ni][reg] - m) * SCL);
          s[mi][ni][reg] = e; sum += e;
        }
      sum += __shfl_xor(sum, 16);
      sum += __shfl_xor(sum, 32);
      float rs = 1.0f / sum;
      int t = tc*32 + ni*16 + l15;
      #pragma unroll
      for (int mi = 0; mi < 4; ++mi){
        f32x4 pv;
        #pragma unroll
        for (int reg = 0; reg < 4; ++reg) pv[reg] = s[mi][ni][reg] * rs;
        store_bf4(&P[h * 4608 + t * 72 + mi*16 + l4*4], pv);
      }
    }
  }
  __syncthreads();
  {
    int wdh = h * 128 + tc * 64;
    f32x4 acc[4][4];
    #pragma unroll
    for (int i = 0; i < 4; ++i)
      #pragma unroll
      for (int j = 0; j < 4; ++j) acc[i][j] = f32x4{0.f,0.f,0.f,0.f};
    const unsigned short* P = R1;
    #pragma unroll
    for (int ks = 0; ks < 2; ++ks){
      int k0 = ks * 32 + l4 * 8;
      bf16x8 a[4], bb[4];
      #pragma unroll
      for (int mi = 0; mi < 4; ++mi)
        a[mi] = *reinterpret_cast<const bf16x8*>(&R2[(wdh + mi*16 + l15) * 72 + k0]);
      #pragma unroll
      for (int ni = 0; ni < 4; ++ni)
        bb[ni] = *reinterpret_cast<const bf16x8*>(&P[h * 4608 + (ni*16 + l15) * 72 + k0]);
      #pragma unroll
      for (int mi = 0; mi < 4; ++mi)
        #pragma unroll
        for (int ni = 0; ni < 4; ++ni)
          acc[mi][ni] = MFMA16(a[mi], bb[ni], acc[mi][ni], 0, 0, 0);
    }
    #pragma unroll
    for (int mi = 0; mi < 4; ++mi){
      int c0 = wdh + mi*16 + l4*4;
      #pragma unroll
      for (int ni = 0; ni < 4; ++ni)
        store_bf4(&R0[(ni*16 + l15) * 264 + c0], acc[mi][ni]);
    }
  }
  __syncthreads();
  {
    f32x4 acc[4][4];
    #pragma unroll
    for (int i = 0; i < 4; ++i)
      #pragma unroll
      for (int j = 0; j < 4; ++j) acc[i][j] = f32x4{0.f,0.f,0.f,0.f};
    #pragma unroll
    for (int ks = 0; ks < 8; ++ks){
      int k0 = ks * 32 + l4 * 8;
      bf16x8 a[4], bb[4];
      #pragma unroll
      for (int mi = 0; mi < 4; ++mi)
        a[mi] = *reinterpret_cast<const bf16x8*>(Wo + (size_t)((wd + mi*16 + l15) * 256 + k0));
      #pragma unroll
      for (int ni = 0; ni < 4; ++ni)
        bb[ni] = *reinterpret_cast<const bf16x8*>(&R0[(ni*16 + l15) * 264 + k0]);
      #pragma unroll
      for (int mi = 0; mi < 4; ++mi)
        #pragma unroll
        for (int ni = 0; ni < 4; ++ni)
          acc[mi][ni] = MFMA16(a[mi], bb[ni], acc[mi][ni], 0, 0, 0);
    }
    #pragma unroll
    for (int mi = 0; mi < 4; ++mi){
      #pragma unroll
      for (int ni = 0; ni < 4; ++ni){
        int t = ni*16 + l15, thi = t >> 3, twi = t & 7;
        size_t base = (size_t)(wd + mi*16 + l4*4) * g.HW + (size_t)thi * g.W + twi;
        #pragma unroll
        for (int reg = 0; reg < 4; ++reg){
          float res = xsrc[base + (size_t)reg * g.HW];
          float v = acc[mi][ni][reg] + res;
          outp[base + (size_t)reg * g.HW] = fmaxf(v, 0.f);
        }
      }
    }
  }
}

extern "C" void kernel_launch(void* const* d_in, const int* in_sizes, int n_in,
                              void* d_out, int out_size, void* d_ws, size_t ws_size,
                              hipStream_t stream) {
  (void)in_sizes; (void)n_in; (void)out_size;
  const float* f0 = (const float*)d_in[0];
  const float* f1 = (const float*)d_in[1];
  const float* f2 = (const float*)d_in[2];
  const float* f3 = (const float*)d_in[3];
  const float* w1 = (const float*)d_in[4];
  const float* w2 = (const float*)d_in[5];
  float* out = (float*)d_out;

  unsigned short* wbf = (unsigned short*)d_ws;            // 4 MB
  const size_t WBF_B   = 4194304;
  const size_t QKV_B   = 22282240;                        // 680*64*256*2
  const size_t need_alias = WBF_B + 3 * QKV_B;            // 71,041,024
  const size_t need_full  = WBF_B + 4 * QKV_B;            // 93,323,264

  wcvt_kernel<<<2048, 256, 0, stream>>>(w1, w2, wbf);

  if (ws_size >= need_alias){
    char* base = (char*)d_ws + WBF_B;
    unsigned short* Qb  = (unsigned short*)(base);
    unsigned short* Kb  = (unsigned short*)(base + QKV_B);
    unsigned short* VTb = (unsigned short*)(base + 2 * QKV_B);
    unsigned short* Ob  = (ws_size >= need_full) ? (unsigned short*)(base + 3 * QKV_B) : Qb;
    for (int phase = 0; phase < 2; ++phase){
      proj_kernel<<<1360, 256, 0, stream>>>(f0, f1, f2, f3, out, wbf, Qb, Kb, VTb, phase);
      attn_kernel<<<680, 256, 0, stream>>>(Qb, Kb, VTb, Ob);
      oproj_kernel<<<680, 256, 0, stream>>>(f0, f1, f2, f3, wbf, Ob, out, phase);
    }
  } else {
    swin_phase<<<680, 256, 0, stream>>>(f0, f1, f2, f3, wbf, out, 0);
    swin_phase<<<680, 256, 0, stream>>>(f0, f1, f2, f3, wbf, out, 1);
  }
}